// Round 1
// baseline (293.679 us; speedup 1.0000x reference)
//
#include <hip/hip_runtime.h>
#include <stdint.h>

// out = (adj @ (X@W + b)) / rowsum(adj)
// B=8, N=4096, C_IN=C_OUT=512, all fp32 in/out. bf16 MFMA internally.
//
// ws layout: hT bf16 [8][512][4096] at offset 0 (32 MiB); Wt bf16 [512][512] after.
// Requires ws_size >= 34,078,720 bytes.

typedef __attribute__((ext_vector_type(4))) float  f32x4;
typedef __attribute__((ext_vector_type(8))) __bf16 bf16x8;
typedef __attribute__((ext_vector_type(4))) __bf16 bf16x4;

#define GLOAD_LDS16(gsrc, ldst)                                                           \
  __builtin_amdgcn_global_load_lds((const __attribute__((address_space(1))) void*)(gsrc), \
                                   (__attribute__((address_space(3))) void*)(ldst), 16, 0, 0)

// ---------------- K0: Wt[n][k] = bf16(W[k][n]), 512x512 ----------------
__global__ void __launch_bounds__(256) k_wt(const float* __restrict__ W,
                                            __bf16* __restrict__ Wt) {
  __shared__ __bf16 t[64][65];
  const int k0 = blockIdx.x * 64, n0 = blockIdx.y * 64;
  const int tid = threadIdx.x;
  const int r = tid >> 2, c4 = (tid & 3) * 16;
#pragma unroll
  for (int j = 0; j < 4; ++j) {
    f32x4 v = *reinterpret_cast<const f32x4*>(W + (size_t)(k0 + r) * 512 + n0 + c4 + j * 4);
#pragma unroll
    for (int q = 0; q < 4; ++q) t[c4 + j * 4 + q][r] = (__bf16)v[q];
  }
  __syncthreads();
#pragma unroll
  for (int j = 0; j < 4; ++j) {
    bf16x4 o;
#pragma unroll
    for (int q = 0; q < 4; ++q) o[q] = t[r][c4 + j * 4 + q];
    *reinterpret_cast<bf16x4*>(Wt + (size_t)(n0 + r) * 512 + k0 + c4 + j * 4) = o;
  }
}

// ---------------- K1: proj  h = X@W + b, stored transposed as hT[b][o][m] bf16 -----
// Tile 128x128, BK=64, 4 waves (2x2), each wave 64x64. Padded LDS (stride 72) -> 2-way max.
__global__ void __launch_bounds__(256) k_proj(const float* __restrict__ X,
                                              const __bf16* __restrict__ Wt,
                                              const float* __restrict__ bias,
                                              __bf16* __restrict__ hT) {
  __shared__ __attribute__((aligned(16))) __bf16 Xs[128][72];
  __shared__ __attribute__((aligned(16))) __bf16 Ws[128][72];
  const int n0 = blockIdx.x * 128;
  const int m0 = blockIdx.y * 128;   // global row over B*N = 32768; 128 | 4096 so batch-uniform
  const int tid = threadIdx.x;
  const int lane = tid & 63, w = tid >> 6;
  const int wr = w >> 1, wc = w & 1;
  const int srow = tid >> 1, scb = (tid & 1) * 32;

  f32x4 acc[4][4] = {};

  for (int k0 = 0; k0 < 512; k0 += 64) {
    // stage X (fp32 -> bf16), 32 elements/thread
    const float* xp = X + (size_t)(m0 + srow) * 512 + k0 + scb;
    f32x4 xv[8];
#pragma unroll
    for (int j = 0; j < 8; ++j) xv[j] = *reinterpret_cast<const f32x4*>(xp + j * 4);
#pragma unroll
    for (int q = 0; q < 4; ++q) {
      bf16x8 o;
#pragma unroll
      for (int e = 0; e < 8; ++e) { const int idx = q * 8 + e; o[e] = (__bf16)xv[idx >> 2][idx & 3]; }
      *reinterpret_cast<bf16x8*>(&Xs[srow][scb + q * 8]) = o;
    }
    // stage Wt tile (already bf16), 32 elements/thread
    const __bf16* wp = Wt + (size_t)(n0 + srow) * 512 + k0 + scb;
#pragma unroll
    for (int q = 0; q < 4; ++q)
      *reinterpret_cast<bf16x8*>(&Ws[srow][scb + q * 8]) =
          *reinterpret_cast<const bf16x8*>(wp + q * 8);
    __syncthreads();

    for (int kk = 0; kk < 64; kk += 32) {
      const int ko = kk + ((lane >> 4) << 3);
      bf16x8 a[4], bb[4];
#pragma unroll
      for (int i = 0; i < 4; ++i)
        a[i] = *reinterpret_cast<const bf16x8*>(&Xs[wr * 64 + i * 16 + (lane & 15)][ko]);
#pragma unroll
      for (int j = 0; j < 4; ++j)
        bb[j] = *reinterpret_cast<const bf16x8*>(&Ws[wc * 64 + j * 16 + (lane & 15)][ko]);
#pragma unroll
      for (int i = 0; i < 4; ++i)
#pragma unroll
        for (int j = 0; j < 4; ++j)
          acc[i][j] = __builtin_amdgcn_mfma_f32_16x16x32_bf16(a[i], bb[j], acc[i][j], 0, 0, 0);
    }
    __syncthreads();
  }

  // epilogue: += bias, cvt bf16, store transposed hT[batch][n][m]
  float bj[4];
#pragma unroll
  for (int j = 0; j < 4; ++j) bj[j] = bias[n0 + wc * 64 + j * 16 + (lane & 15)];
  const int batch = m0 >> 12;
  const int mloc0 = (m0 & 4095) + wr * 64;
#pragma unroll
  for (int i = 0; i < 4; ++i) {
    const int m_in = mloc0 + i * 16 + ((lane >> 4) << 2);  // 4 consecutive rows
#pragma unroll
    for (int j = 0; j < 4; ++j) {
      const int n = n0 + wc * 64 + j * 16 + (lane & 15);
      bf16x4 o;
#pragma unroll
      for (int r = 0; r < 4; ++r) o[r] = (__bf16)(acc[i][j][r] + bj[j]);
      *reinterpret_cast<bf16x4*>(hT + ((size_t)batch * 512 + n) * 4096 + m_in) = o;
    }
  }
}

// ---------------- K2: aggregation  out[n][o] = sum_m adj[n][m]*h[m][o] / deg[n] ----
// 256 blocks (1/CU): batch = bx>>5, m-tile 128 rows. BN = full 512 -> adj read ONCE.
// 8 waves (2x4), wave tile 64x128. A: adj fp32->bf16 reg-staged, XOR-swizzled LDS.
// B: hT bf16 via global_load_lds (pre-swizzled global source). Degree fused.
__global__ void __launch_bounds__(512, 2) k_agg(const float* __restrict__ adj,
                                                const __bf16* __restrict__ hT,
                                                float* __restrict__ out) {
  __shared__ __attribute__((aligned(16))) __bf16 As[128 * 64];
  __shared__ __attribute__((aligned(16))) __bf16 Hs[512 * 64];
  __shared__ float degp[512];
  __shared__ float degf[128];

  const int bx = blockIdx.x;
  const int batch = bx >> 5;
  const int m0 = (bx & 31) * 128;
  const int tid = threadIdx.x;
  const int lane = tid & 63, w = tid >> 6;
  const int wr = w >> 2, wc = w & 3;  // wave tile: rows wr*64, cols wc*128

  const float*  adjb = adj + (size_t)batch * 4096 * 4096;
  const __bf16* hTb  = hT + (size_t)batch * 512 * 4096;

  char* AsB = (char*)As;
  char* HsB = (char*)Hs;

  // A staging: thread -> row (tid>>2), 16 cols from (tid&3)*16
  const int arow = tid >> 2;
  const int acb  = (tid & 3) * 16;
  const int aswz = (arow & 7) << 4;
  const int aw0  = arow * 128 + (((acb * 2) + 0) ^ aswz);
  const int aw1  = arow * 128 + (((acb * 2) + 16) ^ aswz);

  // Hs gload: chunk c = w*8+q covers rows c*8..c*8+7; lane writes block (l&7),
  // so its global source must be block (l&7)^(row&7) where row&7 = (l>>3)&7.
  const int srcblk = (((lane & 7) ^ ((lane >> 3) & 7)) << 3);  // element offset
  const int hrow_l = (lane >> 3);                              // row within chunk

  // fragment read offsets (row&7 == lane&7 for all frag rows)
  const int koffbase = (lane >> 4) << 3;
  const int kswz = (lane & 7) << 4;

  f32x4 acc[4][8] = {};
  float pdeg = 0.f;

  for (int k0 = 0; k0 < 4096; k0 += 64) {
    // issue B staging: 8 chunks of 1 KiB per wave (64 KiB total)
#pragma unroll
    for (int q = 0; q < 8; ++q) {
      const int c = w * 8 + q;
      const __bf16* src = hTb + (size_t)(c * 8 + hrow_l) * 4096 + k0 + srcblk;
      GLOAD_LDS16(src, HsB + c * 1024);
    }
    // stage A: 16 fp32 -> bf16, accumulate degree partials
    const float* ap = adjb + (size_t)(m0 + arow) * 4096 + k0 + acb;
    f32x4 av[4];
#pragma unroll
    for (int j = 0; j < 4; ++j) av[j] = *reinterpret_cast<const f32x4*>(ap + j * 4);
    bf16x8 o0, o1;
#pragma unroll
    for (int e = 0; e < 8; ++e) o0[e] = (__bf16)av[e >> 2][e & 3];
#pragma unroll
    for (int e = 0; e < 8; ++e) o1[e] = (__bf16)av[2 + (e >> 2)][e & 3];
    float s = 0.f;
#pragma unroll
    for (int e = 0; e < 16; ++e) s += av[e >> 2][e & 3];
    pdeg += s;
    *reinterpret_cast<bf16x8*>(AsB + aw0) = o0;
    *reinterpret_cast<bf16x8*>(AsB + aw1) = o1;
    __syncthreads();  // drains vmcnt (gload_lds) + lgkm (ds_write)

    for (int kk = 0; kk < 64; kk += 32) {
      const int ko2 = ((kk + koffbase) * 2) ^ kswz;
      bf16x8 a[4], bb[8];
#pragma unroll
      for (int i = 0; i < 4; ++i) {
        const int row = wr * 64 + i * 16 + (lane & 15);
        a[i] = *reinterpret_cast<const bf16x8*>(AsB + row * 128 + ko2);
      }
#pragma unroll
      for (int j = 0; j < 8; ++j) {
        const int orow = wc * 128 + j * 16 + (lane & 15);
        bb[j] = *reinterpret_cast<const bf16x8*>(HsB + orow * 128 + ko2);
      }
#pragma unroll
      for (int i = 0; i < 4; ++i)
#pragma unroll
        for (int j = 0; j < 8; ++j)
          acc[i][j] = __builtin_amdgcn_mfma_f32_16x16x32_bf16(a[i], bb[j], acc[i][j], 0, 0, 0);
    }
    __syncthreads();
  }

  // degree reduction: 4 partials per row
  degp[tid] = pdeg;
  __syncthreads();
  if (tid < 128)
    degf[tid] = degp[tid * 4] + degp[tid * 4 + 1] + degp[tid * 4 + 2] + degp[tid * 4 + 3];
  __syncthreads();

  // epilogue: divide by degree, store fp32
  float* outb = out + (size_t)batch * 4096 * 512;
#pragma unroll
  for (int i = 0; i < 4; ++i) {
    const int rbase = wr * 64 + i * 16 + ((lane >> 4) << 2);
    float rd[4];
#pragma unroll
    for (int r = 0; r < 4; ++r) rd[r] = 1.0f / degf[rbase + r];
#pragma unroll
    for (int j = 0; j < 8; ++j) {
      const int o = wc * 128 + j * 16 + (lane & 15);
#pragma unroll
      for (int r = 0; r < 4; ++r)
        outb[(size_t)(m0 + rbase + r) * 512 + o] = acc[i][j][r] * rd[r];
    }
  }
}

extern "C" void kernel_launch(void* const* d_in, const int* in_sizes, int n_in,
                              void* d_out, int out_size, void* d_ws, size_t ws_size,
                              hipStream_t stream) {
  (void)in_sizes; (void)n_in; (void)out_size; (void)ws_size;
  const float* X    = (const float*)d_in[0];  // [8,4096,512]
  const float* adj  = (const float*)d_in[1];  // [8,4096,4096]
  const float* W    = (const float*)d_in[2];  // [512,512]
  const float* bias = (const float*)d_in[3];  // [512]
  float* out = (float*)d_out;                 // [8,4096,512] fp32

  char* ws = (char*)d_ws;
  __bf16* hT = (__bf16*)ws;                                   // 32 MiB
  __bf16* Wt = (__bf16*)(ws + (size_t)32 * 1024 * 1024);      // 512 KiB

  k_wt<<<dim3(8, 8), 256, 0, stream>>>(W, Wt);
  k_proj<<<dim3(4, 256), 256, 0, stream>>>(X, Wt, bias, hT);
  k_agg<<<dim3(256), 512, 0, stream>>>(adj, hT, out);
}

// Round 2
// 289.666 us; speedup vs baseline: 1.0139x; 1.0139x over previous
//
#include <hip/hip_runtime.h>
#include <stdint.h>

// out = (adj @ (X@W + b)) / rowsum(adj)
// B=8, N=4096, C_IN=C_OUT=512, all fp32 in/out. bf16 MFMA internally.
//
// ws layout: hT bf16 [8][512][4096] at offset 0 (32 MiB); Wt bf16 [512][512] after.

typedef __attribute__((ext_vector_type(4))) float  f32x4;
typedef __attribute__((ext_vector_type(8))) __bf16 bf16x8;
typedef __attribute__((ext_vector_type(4))) __bf16 bf16x4;

#define GLOAD_LDS16(gsrc, ldst)                                                           \
  __builtin_amdgcn_global_load_lds((const __attribute__((address_space(1))) void*)(gsrc), \
                                   (__attribute__((address_space(3))) void*)(ldst), 16, 0, 0)

#define MEMFENCE asm volatile("" ::: "memory")

// ---------------- K0: Wt[n][k] = bf16(W[k][n]), 512x512 ----------------
__global__ void __launch_bounds__(256) k_wt(const float* __restrict__ W,
                                            __bf16* __restrict__ Wt) {
  __shared__ __bf16 t[64][65];
  const int k0 = blockIdx.x * 64, n0 = blockIdx.y * 64;
  const int tid = threadIdx.x;
  const int r = tid >> 2, c4 = (tid & 3) * 16;
#pragma unroll
  for (int j = 0; j < 4; ++j) {
    f32x4 v = *reinterpret_cast<const f32x4*>(W + (size_t)(k0 + r) * 512 + n0 + c4 + j * 4);
#pragma unroll
    for (int q = 0; q < 4; ++q) t[c4 + j * 4 + q][r] = (__bf16)v[q];
  }
  __syncthreads();
#pragma unroll
  for (int j = 0; j < 4; ++j) {
    bf16x4 o;
#pragma unroll
    for (int q = 0; q < 4; ++q) o[q] = t[r][c4 + j * 4 + q];
    *reinterpret_cast<bf16x4*>(Wt + (size_t)(n0 + r) * 512 + k0 + c4 + j * 4) = o;
  }
}

// ---------------- K1: proj  h = X@W + b, stored transposed as hT[b][o][m] bf16 -----
__global__ void __launch_bounds__(256) k_proj(const float* __restrict__ X,
                                              const __bf16* __restrict__ Wt,
                                              const float* __restrict__ bias,
                                              __bf16* __restrict__ hT) {
  __shared__ __attribute__((aligned(16))) __bf16 Xs[128][72];
  __shared__ __attribute__((aligned(16))) __bf16 Ws[128][72];
  const int n0 = blockIdx.x * 128;
  const int m0 = blockIdx.y * 128;
  const int tid = threadIdx.x;
  const int lane = tid & 63, w = tid >> 6;
  const int wr = w >> 1, wc = w & 1;
  const int srow = tid >> 1, scb = (tid & 1) * 32;

  f32x4 acc[4][4] = {};

  for (int k0 = 0; k0 < 512; k0 += 64) {
    const float* xp = X + (size_t)(m0 + srow) * 512 + k0 + scb;
    f32x4 xv[8];
#pragma unroll
    for (int j = 0; j < 8; ++j) xv[j] = *reinterpret_cast<const f32x4*>(xp + j * 4);
#pragma unroll
    for (int q = 0; q < 4; ++q) {
      bf16x8 o;
#pragma unroll
      for (int e = 0; e < 8; ++e) { const int idx = q * 8 + e; o[e] = (__bf16)xv[idx >> 2][idx & 3]; }
      *reinterpret_cast<bf16x8*>(&Xs[srow][scb + q * 8]) = o;
    }
    const __bf16* wp = Wt + (size_t)(n0 + srow) * 512 + k0 + scb;
#pragma unroll
    for (int q = 0; q < 4; ++q)
      *reinterpret_cast<bf16x8*>(&Ws[srow][scb + q * 8]) =
          *reinterpret_cast<const bf16x8*>(wp + q * 8);
    __syncthreads();

    for (int kk = 0; kk < 64; kk += 32) {
      const int ko = kk + ((lane >> 4) << 3);
      bf16x8 a[4], bb[4];
#pragma unroll
      for (int i = 0; i < 4; ++i)
        a[i] = *reinterpret_cast<const bf16x8*>(&Xs[wr * 64 + i * 16 + (lane & 15)][ko]);
#pragma unroll
      for (int j = 0; j < 4; ++j)
        bb[j] = *reinterpret_cast<const bf16x8*>(&Ws[wc * 64 + j * 16 + (lane & 15)][ko]);
#pragma unroll
      for (int i = 0; i < 4; ++i)
#pragma unroll
        for (int j = 0; j < 4; ++j)
          acc[i][j] = __builtin_amdgcn_mfma_f32_16x16x32_bf16(a[i], bb[j], acc[i][j], 0, 0, 0);
    }
    __syncthreads();
  }

  float bj[4];
#pragma unroll
  for (int j = 0; j < 4; ++j) bj[j] = bias[n0 + wc * 64 + j * 16 + (lane & 15)];
  const int batch = m0 >> 12;
  const int mloc0 = (m0 & 4095) + wr * 64;
#pragma unroll
  for (int i = 0; i < 4; ++i) {
    const int m_in = mloc0 + i * 16 + ((lane >> 4) << 2);
#pragma unroll
    for (int j = 0; j < 4; ++j) {
      const int n = n0 + wc * 64 + j * 16 + (lane & 15);
      bf16x4 o;
#pragma unroll
      for (int r = 0; r < 4; ++r) o[r] = (__bf16)(acc[i][j][r] + bj[j]);
      *reinterpret_cast<bf16x4*>(hT + ((size_t)batch * 512 + n) * 4096 + m_in) = o;
    }
  }
}

// ---------------- K2: aggregation  out[n][o] = sum_m adj[n][m]*h[m][o] / deg[n] ----
// batch<->XCD swizzle: all 32 blocks of a batch land on one XCD -> hT slice (4 MiB)
// is L2-resident (was 1 GiB of HBM re-fetch). Hs double-buffered via raw s_barrier +
// counted vmcnt so tile t+1 loads stay in flight across MFMA(t). As single-buffered,
// rewritten between the two barriers (adj regs issued early, T14).
__global__ void __launch_bounds__(512) k_agg(const float* __restrict__ adj,
                                             const __bf16* __restrict__ hT,
                                             float* __restrict__ out) {
  __shared__ __attribute__((aligned(16))) __bf16 As[128 * 64];
  __shared__ __attribute__((aligned(16))) __bf16 Hs[2][512 * 64];
  __shared__ float degp[512];
  __shared__ float degf[128];

  const int bx = ((int)blockIdx.x & 7) * 32 + ((int)blockIdx.x >> 3);  // XCD x <-> batch x
  const int batch = bx >> 5;
  const int m0 = (bx & 31) * 128;
  const int tid = threadIdx.x;
  const int lane = tid & 63, w = tid >> 6;
  const int wr = w >> 2, wc = w & 3;  // wave tile: rows wr*64, cols wc*128

  const float*  adjb = adj + (size_t)batch * 4096 * 4096;
  const __bf16* hTb  = hT + (size_t)batch * 512 * 4096;

  char* AsB = (char*)As;

  // A staging addresses (verified r1): thread -> row tid>>2, 16 cols from (tid&3)*16
  const int arow = tid >> 2;
  const int acb  = (tid & 3) * 16;
  const int aswz = (arow & 7) << 4;
  const int aw0  = arow * 128 + (((acb * 2) + 0) ^ aswz);
  const int aw1  = arow * 128 + (((acb * 2) + 16) ^ aswz);
  const float* adjrow = adjb + (size_t)(m0 + arow) * 4096 + acb;

  // Hs gload source pre-swizzle (verified r1)
  const int srcblk = (((lane & 7) ^ ((lane >> 3) & 7)) << 3);
  const int hrow_l = (lane >> 3);

  // fragment read swizzle
  const int koffbase = (lane >> 4) << 3;
  const int kswz = (lane & 7) << 4;

  f32x4 acc[4][8] = {};
  float pdeg = 0.f;
  f32x4 av[4];

  auto load_adj = [&](int k0) {
#pragma unroll
    for (int j = 0; j < 4; ++j) av[j] = *reinterpret_cast<const f32x4*>(adjrow + k0 + j * 4);
  };
  auto issue_hs = [&](int k0, int buf) {
    char* dst = (char*)Hs[buf];
#pragma unroll
    for (int q = 0; q < 8; ++q) {
      const int c = w * 8 + q;
      const __bf16* src = hTb + (size_t)(c * 8 + hrow_l) * 4096 + k0 + srcblk;
      GLOAD_LDS16(src, dst + c * 1024);
    }
  };
  auto write_as = [&]() {
    bf16x8 o0, o1;
#pragma unroll
    for (int e = 0; e < 8; ++e) o0[e] = (__bf16)av[e >> 2][e & 3];
#pragma unroll
    for (int e = 0; e < 8; ++e) o1[e] = (__bf16)av[2 + (e >> 2)][e & 3];
    float s = 0.f;
#pragma unroll
    for (int e = 0; e < 16; ++e) s += av[e >> 2][e & 3];
    pdeg += s;
    *reinterpret_cast<bf16x8*>(AsB + aw0) = o0;
    *reinterpret_cast<bf16x8*>(AsB + aw1) = o1;
  };
  auto compute = [&](int buf) {
    char* HsB = (char*)Hs[buf];
#pragma unroll
    for (int kk = 0; kk < 64; kk += 32) {
      const int ko2 = ((kk + koffbase) * 2) ^ kswz;
      bf16x8 a[4], bb[8];
#pragma unroll
      for (int i = 0; i < 4; ++i) {
        const int row = wr * 64 + i * 16 + (lane & 15);
        a[i] = *reinterpret_cast<const bf16x8*>(AsB + row * 128 + ko2);
      }
#pragma unroll
      for (int j = 0; j < 8; ++j) {
        const int orow = wc * 128 + j * 16 + (lane & 15);
        bb[j] = *reinterpret_cast<const bf16x8*>(HsB + orow * 128 + ko2);
      }
      asm volatile("s_waitcnt lgkmcnt(0)" ::: "memory");
      __builtin_amdgcn_sched_barrier(0);  // rule 18: keep MFMA below the wait
      __builtin_amdgcn_s_setprio(1);
#pragma unroll
      for (int i = 0; i < 4; ++i)
#pragma unroll
        for (int j = 0; j < 8; ++j)
          acc[i][j] = __builtin_amdgcn_mfma_f32_16x16x32_bf16(a[i], bb[j], acc[i][j], 0, 0, 0);
      __builtin_amdgcn_s_setprio(0);
    }
  };

  // ---- prologue: stage tile 0 ----
  load_adj(0);
  issue_hs(0, 0);
  write_as();  // compiler inserts vmcnt for av
  asm volatile("s_waitcnt vmcnt(0) lgkmcnt(0)" ::: "memory");
  __builtin_amdgcn_s_barrier();
  MEMFENCE;

  // ---- main loop: compute t, prefetch t+1 ----
  for (int t = 0; t < 63; ++t) {
    const int c = t & 1;
    load_adj((t + 1) * 64);   // 4 vmem, oldest -> retire first
    issue_hs((t + 1) * 64, c ^ 1);  // 8 vmem in flight across MFMA
    compute(c);
    MEMFENCE;
    __builtin_amdgcn_s_barrier();  // all waves done reading As(t)
    MEMFENCE;
    write_as();                    // vmcnt for av auto; ds_write As(t+1)
    asm volatile("s_waitcnt vmcnt(0) lgkmcnt(0)" ::: "memory");
    __builtin_amdgcn_s_barrier();  // As(t+1) + Hs[c^1] ready
    MEMFENCE;
  }
  compute(1);  // t=63

  // ---- degree reduction ----
  __syncthreads();
  degp[tid] = pdeg;
  __syncthreads();
  if (tid < 128)
    degf[tid] = degp[tid * 4] + degp[tid * 4 + 1] + degp[tid * 4 + 2] + degp[tid * 4 + 3];
  __syncthreads();

  // ---- epilogue ----
  float* outb = out + (size_t)batch * 4096 * 512;
#pragma unroll
  for (int i = 0; i < 4; ++i) {
    const int rbase = wr * 64 + i * 16 + ((lane >> 4) << 2);
    float rd[4];
#pragma unroll
    for (int r = 0; r < 4; ++r) rd[r] = 1.0f / degf[rbase + r];
#pragma unroll
    for (int j = 0; j < 8; ++j) {
      const int o = wc * 128 + j * 16 + (lane & 15);
#pragma unroll
      for (int r = 0; r < 4; ++r)
        outb[(size_t)(m0 + rbase + r) * 512 + o] = acc[i][j][r] * rd[r];
    }
  }
}

extern "C" void kernel_launch(void* const* d_in, const int* in_sizes, int n_in,
                              void* d_out, int out_size, void* d_ws, size_t ws_size,
                              hipStream_t stream) {
  (void)in_sizes; (void)n_in; (void)out_size; (void)ws_size;
  const float* X    = (const float*)d_in[0];  // [8,4096,512]
  const float* adj  = (const float*)d_in[1];  // [8,4096,4096]
  const float* W    = (const float*)d_in[2];  // [512,512]
  const float* bias = (const float*)d_in[3];  // [512]
  float* out = (float*)d_out;                 // [8,4096,512] fp32

  char* ws = (char*)d_ws;
  __bf16* hT = (__bf16*)ws;                                   // 32 MiB
  __bf16* Wt = (__bf16*)(ws + (size_t)32 * 1024 * 1024);      // 512 KiB

  k_wt<<<dim3(8, 8), 256, 0, stream>>>(W, Wt);
  k_proj<<<dim3(4, 256), 256, 0, stream>>>(X, Wt, bias, hT);
  k_agg<<<dim3(256), 512, 0, stream>>>(adj, hT, out);
}